// Round 5
// baseline (7395.070 us; speedup 1.0000x reference)
//
#include <hip/hip_runtime.h>
#include <math.h>

#define NB    8
#define NE    1024
#define DDIM  256
#define TTOK  4096
#define BBATCH 16
#define NTOK  (BBATCH*TTOK)   // 65536

#define TM    64      // tokens per block (= lanes of a wave; all 4 waves share)
#define RSTR  257     // res_s row stride (floats): 2-way bank aliasing on b128 = free

// ---------- h[c] = 0.5*sum(e*e) with numpy pairwise-sum semantics ----------
__global__ void hsum_kernel(const float* __restrict__ books, float* __restrict__ hg) {
    int c = blockIdx.x * blockDim.x + threadIdx.x;
    if (c >= NB * NE) return;
    const float* e = books + (size_t)c * DDIM;
    float blk[2];
    for (int half = 0; half < 2; ++half) {
        const float* a = e + half * 128;
        float r[8];
        #pragma unroll
        for (int j = 0; j < 8; ++j) {
            float s = a[j] * a[j];
            asm volatile("" : "+v"(s));
            r[j] = s;
        }
        for (int i = 8; i < 128; i += 8) {
            #pragma unroll
            for (int j = 0; j < 8; ++j) {
                float s = a[i + j] * a[i + j];
                asm volatile("" : "+v"(s));
                r[j] = r[j] + s;
            }
        }
        blk[half] = ((r[0] + r[1]) + (r[2] + r[3])) + ((r[4] + r[5]) + (r[6] + r[7]));
    }
    hg[c] = 0.5f * (blk[0] + blk[1]);
}

// ---------- z (B,D,T) -> zt[token][dim] ----------
__global__ void txin_kernel(const float* __restrict__ z, float* __restrict__ zt) {
    __shared__ float ld[64 * 68];
    int t0 = blockIdx.x * 64, d0 = blockIdx.y * 64, b = blockIdx.z;
    int tid = threadIdx.x;
    {
        int dd = tid >> 2, t4 = (tid & 3) * 16;
        const float* zp = z + ((size_t)b * DDIM + d0 + dd) * TTOK + t0 + t4;
        #pragma unroll
        for (int c = 0; c < 16; c += 4)
            *(float4*)&ld[dd * 68 + t4 + c] = *(const float4*)(zp + c);
    }
    __syncthreads();
    {
        int t = tid >> 2, d4 = (tid & 3) * 16;
        float* rp = zt + ((size_t)b * TTOK + t0 + t) * DDIM + d0 + d4;
        #pragma unroll
        for (int c = 0; c < 16; c += 4) {
            float4 o;
            o.x = ld[(size_t)(d4 + c + 0) * 68 + t];
            o.y = ld[(size_t)(d4 + c + 1) * 68 + t];
            o.z = ld[(size_t)(d4 + c + 2) * 68 + t];
            o.w = ld[(size_t)(d4 + c + 3) * 68 + t];
            *(float4*)(rp + c) = o;
        }
    }
}

// ---------- books[b][n][k] -> bt[b][k][n]  (so code loads are n-contiguous) ----------
__global__ void tbooks_kernel(const float* __restrict__ books, float* __restrict__ bt) {
    __shared__ float ld[64 * 68];
    int n0 = blockIdx.x * 64, k0 = blockIdx.y * 64, b = blockIdx.z;
    int tid = threadIdx.x;
    const float* in = books + (size_t)b * NE * DDIM;
    float* out = bt + (size_t)b * DDIM * NE;
    {
        int nn = tid >> 2, kc = (tid & 3) * 16;
        const float* ip = in + (size_t)(n0 + nn) * DDIM + k0 + kc;
        #pragma unroll
        for (int c = 0; c < 16; c += 4)
            *(float4*)&ld[nn * 68 + kc + c] = *(const float4*)(ip + c);
    }
    __syncthreads();
    {
        int kk = tid >> 2, nc = (tid & 3) * 16;
        float* op = out + (size_t)(k0 + kk) * NE + n0 + nc;
        #pragma unroll
        for (int c = 0; c < 16; c += 4) {
            float4 o;
            o.x = ld[(size_t)(nc + c + 0) * 68 + kk];
            o.y = ld[(size_t)(nc + c + 1) * 68 + kk];
            o.z = ld[(size_t)(nc + c + 2) * 68 + kk];
            o.w = ld[(size_t)(nc + c + 3) * 68 + kk];
            *(float4*)(op + c) = o;
        }
    }
}

// ---------- main scan: lane = token, codes via wave-uniform scalar loads ----------
// score chain identical to the validated R4 kernel: acc from 0, k-ascending
// single-accumulator fmaf, one subtract of h at the end.
__launch_bounds__(256)
__global__ void vq_main(const float* __restrict__ books,
                        const float* __restrict__ bt,
                        const float* __restrict__ hg,
                        const float* __restrict__ zt,
                        int* __restrict__ idxg) {
    __shared__ float res_s[TM * RSTR];   // 64.25 KB residual [tok][k]
    __shared__ float bv_s[4 * TM];
    __shared__ int   bn_s[4 * TM];
    __shared__ int   bidx_s[TM];

    const int tid  = threadIdx.x;
    const int lane = tid & 63;
    const int w    = __builtin_amdgcn_readfirstlane(tid >> 6);   // 0..3, wave-uniform
    const size_t tok0 = (size_t)blockIdx.x * TM;

    // stage residual = z tokens into LDS [tok][k] (stride RSTR)
    {
        int m = tid >> 2, qc = (tid & 3) * 64;
        const float* zp = zt + (tok0 + m) * DDIM + qc;
        float* rp = &res_s[m * RSTR + qc];
        #pragma unroll
        for (int c = 0; c < 64; c += 4)
            *(float4*)(rp + c) = *(const float4*)(zp + c);
    }
    __syncthreads();

    for (int b = 0; b < NB; ++b) {
        const float* btb = bt + (size_t)b * DDIM * NE;   // [k][n]
        const float* cb  = books + (size_t)b * NE * DDIM; // [n][k]
        const float* hb  = hg + b * NE;

        float bv = -3.4e38f; int bn = 0;

        for (int p = 0; p < 16; ++p) {
            const int n0 = p * 64 + w * 16;              // wave-uniform code base
            float acc[16];
            #pragma unroll
            for (int i = 0; i < 16; ++i) acc[i] = 0.0f;

            #pragma unroll 2
            for (int k0 = 0; k0 < DDIM; k0 += 4) {
                float4 rv = *(const float4*)&res_s[lane * RSTR + k0];
                const float* c0 = btb + (size_t)(k0 + 0) * NE + n0;
                const float* c1 = btb + (size_t)(k0 + 1) * NE + n0;
                const float* c2 = btb + (size_t)(k0 + 2) * NE + n0;
                const float* c3 = btb + (size_t)(k0 + 3) * NE + n0;
                #pragma unroll
                for (int i = 0; i < 16; ++i) {
                    float a = acc[i];
                    a = __builtin_fmaf(rv.x, c0[i], a);
                    a = __builtin_fmaf(rv.y, c1[i], a);
                    a = __builtin_fmaf(rv.z, c2[i], a);
                    a = __builtin_fmaf(rv.w, c3[i], a);
                    acc[i] = a;
                }
            }
            // score = dot - h; n ascending within wave -> strict '>' keeps first max
            #pragma unroll
            for (int i = 0; i < 16; ++i) {
                float v = acc[i] - hb[n0 + i];
                if (v > bv) { bv = v; bn = n0 + i; }
            }
        }
        bv_s[w * TM + lane] = bv;
        bn_s[w * TM + lane] = bn;
        __syncthreads();

        if (tid < TM) {
            float v = bv_s[tid]; int n = bn_s[tid];
            #pragma unroll
            for (int ww = 1; ww < 4; ++ww) {
                float ov = bv_s[ww * TM + tid];
                int   on = bn_s[ww * TM + tid];
                if (ov > v || (ov == v && on < n)) { v = ov; n = on; }
            }
            bidx_s[tid] = n;
            idxg[(tok0 + tid) * NB + b] = n;
        }
        __syncthreads();

        // residual update r = r - q (plain fp32 subs, matches reference chain)
        {
            int m = tid >> 2, qc = (tid & 3) * 64;
            const float* qrow = cb + (size_t)bidx_s[m] * DDIM + qc;
            float* rrow = &res_s[m * RSTR + qc];
            #pragma unroll
            for (int c = 0; c < 64; c += 4) {
                float4 qv = *(const float4*)(qrow + c);
                float4 rv = *(float4*)(rrow + c);
                rv.x = rv.x - qv.x; rv.y = rv.y - qv.y;
                rv.z = rv.z - qv.z; rv.w = rv.w - qv.w;
                *(float4*)(rrow + c) = rv;
            }
        }
        __syncthreads();
    }
}

// ---------- replay: q_sum with the reference's exact fp32 op order ----------
__global__ void replay_kernel(const float* __restrict__ books,
                              const int* __restrict__ idxg,
                              float* __restrict__ zt) {
    size_t gid = (size_t)blockIdx.x * 256 + threadIdx.x;
    size_t tok = gid >> 6;
    int d4 = (int)(gid & 63) * 4;
    const int* ip = idxg + tok * NB;
    float4 r = *(const float4*)&zt[tok * DDIM + d4];
    float4 qs = make_float4(0.f, 0.f, 0.f, 0.f);
    #pragma unroll
    for (int b = 0; b < NB; ++b) {
        int idx = ip[b];
        float4 q = *(const float4*)&books[((size_t)b * NE + idx) * DDIM + d4];
        float t1;
        t1 = q.x - r.x; qs.x = qs.x + t1; qs.x = qs.x + r.x; r.x = r.x - q.x;
        t1 = q.y - r.y; qs.y = qs.y + t1; qs.y = qs.y + r.y; r.y = r.y - q.y;
        t1 = q.z - r.z; qs.z = qs.z + t1; qs.z = qs.z + r.z; r.z = r.z - q.z;
        t1 = q.w - r.w; qs.w = qs.w + t1; qs.w = qs.w + r.w; r.w = r.w - q.w;
    }
    *(float4*)&zt[tok * DDIM + d4] = qs;
}

// ---------- out (B,D,T) = transpose of q_sum[token][dim] ----------
__global__ void fin_kernel(const float* __restrict__ qst, float* __restrict__ out) {
    __shared__ float ld[64 * 68];
    int t0 = blockIdx.x * 64, d0 = blockIdx.y * 64, b = blockIdx.z;
    int tid = threadIdx.x;
    {
        int t = tid >> 2, d4 = (tid & 3) * 16;
        const float* rp = qst + ((size_t)b * TTOK + t0 + t) * DDIM + d0 + d4;
        #pragma unroll
        for (int c = 0; c < 16; c += 4)
            *(float4*)&ld[t * 68 + d4 + c] = *(const float4*)(rp + c);
    }
    __syncthreads();
    {
        int dd = tid >> 2, t4 = (tid & 3) * 16;
        float* op = out + ((size_t)b * DDIM + d0 + dd) * TTOK + t0 + t4;
        #pragma unroll
        for (int c = 0; c < 16; c += 4) {
            float4 o;
            o.x = ld[(size_t)(t4 + c + 0) * 68 + dd];
            o.y = ld[(size_t)(t4 + c + 1) * 68 + dd];
            o.z = ld[(size_t)(t4 + c + 2) * 68 + dd];
            o.w = ld[(size_t)(t4 + c + 3) * 68 + dd];
            *(float4*)(op + c) = o;
        }
    }
}

extern "C" void kernel_launch(void* const* d_in, const int* in_sizes, int n_in,
                              void* d_out, int out_size, void* d_ws, size_t ws_size,
                              hipStream_t stream) {
    const float* z     = (const float*)d_in[0];
    const float* books = (const float*)d_in[1];
    float* out = (float*)d_out;

    float* hg   = (float*)d_ws;                          // 8192 floats
    int*   idxg = (int*)(hg + (size_t)NB * NE);          // 65536*8 ints (2 MB)
    float* bt   = (float*)(idxg + (size_t)NTOK * NB);    // 8 MB transposed books
    float* zt   = bt + (size_t)NB * DDIM * NE;           // 64 MB token-major

    hsum_kernel<<<(NB * NE + 255) / 256, 256, 0, stream>>>(books, hg);
    tbooks_kernel<<<dim3(NE / 64, DDIM / 64, NB), 256, 0, stream>>>(books, bt);
    txin_kernel<<<dim3(TTOK / 64, DDIM / 64, BBATCH), 256, 0, stream>>>(z, zt);
    vq_main<<<NTOK / TM, 256, 0, stream>>>(books, bt, hg, zt, idxg);
    replay_kernel<<<NTOK * 64 / 256, 256, 0, stream>>>(books, idxg, zt);
    fin_kernel<<<dim3(TTOK / 64, DDIM / 64, BBATCH), 256, 0, stream>>>(zt, out);
}

// Round 6
// 3865.711 us; speedup vs baseline: 1.9130x; 1.9130x over previous
//
#include <hip/hip_runtime.h>
#include <math.h>

#define NB    8
#define NE    1024
#define DDIM  256
#define TTOK  4096
#define BBATCH 16
#define NTOK  (BBATCH*TTOK)   // 65536

#define TM    64      // tokens per block
#define RSTR  260     // res_s row stride: 16B-aligned (260*4=65*16), banks spread by 4
#define CSTR  12      // code row stride: 8 k + 4 pad; 16B-aligned (48B), 2-way banks = free
#define KCH   8       // k per staged chunk

// ---------- h[c] = 0.5*sum(e*e) with numpy pairwise-sum semantics ----------
__global__ void hsum_kernel(const float* __restrict__ books, float* __restrict__ hg) {
    int c = blockIdx.x * blockDim.x + threadIdx.x;
    if (c >= NB * NE) return;
    const float* e = books + (size_t)c * DDIM;
    float blk[2];
    for (int half = 0; half < 2; ++half) {
        const float* a = e + half * 128;
        float r[8];
        #pragma unroll
        for (int j = 0; j < 8; ++j) {
            float s = a[j] * a[j];
            asm volatile("" : "+v"(s));
            r[j] = s;
        }
        for (int i = 8; i < 128; i += 8) {
            #pragma unroll
            for (int j = 0; j < 8; ++j) {
                float s = a[i + j] * a[i + j];
                asm volatile("" : "+v"(s));
                r[j] = r[j] + s;
            }
        }
        blk[half] = ((r[0] + r[1]) + (r[2] + r[3])) + ((r[4] + r[5]) + (r[6] + r[7]));
    }
    hg[c] = 0.5f * (blk[0] + blk[1]);
}

// ---------- z (B,D,T) -> zt[token][dim] ----------
__global__ void txin_kernel(const float* __restrict__ z, float* __restrict__ zt) {
    __shared__ float ld[64 * 68];
    int t0 = blockIdx.x * 64, d0 = blockIdx.y * 64, b = blockIdx.z;
    int tid = threadIdx.x;
    {
        int dd = tid >> 2, t4 = (tid & 3) * 16;
        const float* zp = z + ((size_t)b * DDIM + d0 + dd) * TTOK + t0 + t4;
        #pragma unroll
        for (int c = 0; c < 16; c += 4)
            *(float4*)&ld[dd * 68 + t4 + c] = *(const float4*)(zp + c);
    }
    __syncthreads();
    {
        int t = tid >> 2, d4 = (tid & 3) * 16;
        float* rp = zt + ((size_t)b * TTOK + t0 + t) * DDIM + d0 + d4;
        #pragma unroll
        for (int c = 0; c < 16; c += 4) {
            float4 o;
            o.x = ld[(size_t)(d4 + c + 0) * 68 + t];
            o.y = ld[(size_t)(d4 + c + 1) * 68 + t];
            o.z = ld[(size_t)(d4 + c + 2) * 68 + t];
            o.w = ld[(size_t)(d4 + c + 3) * 68 + t];
            *(float4*)(rp + c) = o;
        }
    }
}

// ---------- books[b][n][k] -> bt[b][k][n] ----------
__global__ void tbooks_kernel(const float* __restrict__ books, float* __restrict__ bt) {
    __shared__ float ld[64 * 68];
    int n0 = blockIdx.x * 64, k0 = blockIdx.y * 64, b = blockIdx.z;
    int tid = threadIdx.x;
    const float* in = books + (size_t)b * NE * DDIM;
    float* out = bt + (size_t)b * DDIM * NE;
    {
        int nn = tid >> 2, kc = (tid & 3) * 16;
        const float* ip = in + (size_t)(n0 + nn) * DDIM + k0 + kc;
        #pragma unroll
        for (int c = 0; c < 16; c += 4)
            *(float4*)&ld[nn * 68 + kc + c] = *(const float4*)(ip + c);
    }
    __syncthreads();
    {
        int kk = tid >> 2, nc = (tid & 3) * 16;
        float* op = out + (size_t)(k0 + kk) * NE + n0 + nc;
        #pragma unroll
        for (int c = 0; c < 16; c += 4) {
            float4 o;
            o.x = ld[(size_t)(nc + c + 0) * 68 + kk];
            o.y = ld[(size_t)(nc + c + 1) * 68 + kk];
            o.z = ld[(size_t)(nc + c + 2) * 68 + kk];
            o.w = ld[(size_t)(nc + c + 3) * 68 + kk];
            *(float4*)(op + c) = o;
        }
    }
}

// ---------- main scan: 8x8 register tile, codes staged in LDS with prefetch ----------
// Numerics identical to the validated R4 kernel: acc from 0, strict k-ascending
// single-accumulator fmaf chain, one subtract of h at the end, plain-sub update.
__launch_bounds__(256, 2)
__global__ void vq_main(const float* __restrict__ books,
                        const float* __restrict__ bt,
                        const float* __restrict__ hg,
                        const float* __restrict__ zt,
                        int* __restrict__ idxg) {
    __shared__ float res_s[TM * RSTR];     // 66.6 KB residual [tok][k]
    __shared__ float cs[256 * CSTR];       // 12.3 KB code chunk [code][k]
    __shared__ int   bidx_s[TM];

    const int tid = threadIdx.x;
    const int tx  = tid & 31;              // code residue within pass
    const int ty  = tid >> 5;              // token group (8 tokens each)
    const size_t tok0 = (size_t)blockIdx.x * TM;

    // stage residual = z tokens into LDS
    {
        int m = tid >> 2, qc = (tid & 3) * 64;
        const float* zp = zt + (tok0 + m) * DDIM + qc;
        float* rp = &res_s[m * RSTR + qc];
        #pragma unroll
        for (int c = 0; c < 64; c += 4)
            *(float4*)(rp + c) = *(const float4*)(zp + c);
    }
    __syncthreads();

    for (int b = 0; b < NB; ++b) {
        const float* btb = bt + (size_t)b * DDIM * NE;    // [k][n]
        const float* cb  = books + (size_t)b * NE * DDIM; // [n][k]
        const float* hb  = hg + b * NE;

        float bv[8]; int bn[8];
        #pragma unroll
        for (int j = 0; j < 8; ++j) { bv[j] = -3.4e38f; bn[j] = 0; }

        for (int p = 0; p < 4; ++p) {
            const int n0 = p * 256;
            float acc[8][8];
            #pragma unroll
            for (int j = 0; j < 8; ++j)
                #pragma unroll
                for (int i = 0; i < 8; ++i) acc[j][i] = 0.0f;

            // prologue: stage chunk 0 (k = 0..7 of this pass's 256 codes)
            {
                float cur[KCH];
                #pragma unroll
                for (int r = 0; r < KCH; ++r)
                    cur[r] = btb[(size_t)r * NE + n0 + tid];
                #pragma unroll
                for (int r = 0; r < KCH; ++r)
                    cs[tid * CSTR + r] = cur[r];
            }
            __syncthreads();

            for (int ch = 0; ch < DDIM / KCH; ++ch) {
                float nxt[KCH];
                if (ch < DDIM / KCH - 1) {
                    const float* gp = btb + (size_t)(ch + 1) * KCH * NE + n0 + tid;
                    #pragma unroll
                    for (int r = 0; r < KCH; ++r) nxt[r] = gp[(size_t)r * NE];
                }
                const int kb = ch * KCH;
                #pragma unroll
                for (int k4 = 0; k4 < KCH; k4 += 4) {
                    float4 rv[8], cv[8];
                    #pragma unroll
                    for (int j = 0; j < 8; ++j)
                        rv[j] = *(const float4*)&res_s[(ty * 8 + j) * RSTR + kb + k4];
                    #pragma unroll
                    for (int i = 0; i < 8; ++i)
                        cv[i] = *(const float4*)&cs[(tx + 32 * i) * CSTR + k4];
                    #pragma unroll
                    for (int j = 0; j < 8; ++j)
                        #pragma unroll
                        for (int i = 0; i < 8; ++i) {
                            float a = acc[j][i];
                            a = __builtin_fmaf(rv[j].x, cv[i].x, a);
                            a = __builtin_fmaf(rv[j].y, cv[i].y, a);
                            a = __builtin_fmaf(rv[j].z, cv[i].z, a);
                            a = __builtin_fmaf(rv[j].w, cv[i].w, a);
                            acc[j][i] = a;
                        }
                }
                __syncthreads();
                if (ch < DDIM / KCH - 1) {
                    #pragma unroll
                    for (int r = 0; r < KCH; ++r) cs[tid * CSTR + r] = nxt[r];
                }
                __syncthreads();
            }
            // score = dot - h; n ascending (i asc, passes asc) -> '>' keeps first max
            #pragma unroll
            for (int i = 0; i < 8; ++i) {
                int n = n0 + tx + 32 * i;
                float hh = hb[n];
                #pragma unroll
                for (int j = 0; j < 8; ++j) {
                    float v = acc[j][i] - hh;
                    if (v > bv[j]) { bv[j] = v; bn[j] = n; }
                }
            }
        }
        // butterfly argmax across the 32 tx lanes of each ty group
        #pragma unroll
        for (int j = 0; j < 8; ++j) {
            float v = bv[j]; int n = bn[j];
            #pragma unroll
            for (int m5 = 16; m5; m5 >>= 1) {
                float ov = __shfl_xor(v, m5, 64);
                int   on = __shfl_xor(n, m5, 64);
                if (ov > v || (ov == v && on < n)) { v = ov; n = on; }
            }
            if (tx == 0) bidx_s[ty * 8 + j] = n;
        }
        __syncthreads();
        if (tid < TM) idxg[(tok0 + tid) * NB + b] = bidx_s[tid];
        // residual update r = r - q (plain fp32 subs, matches reference chain)
        {
            int m = tid >> 2, qc = (tid & 3) * 64;
            const float* qrow = cb + (size_t)bidx_s[m] * DDIM + qc;
            float* rrow = &res_s[m * RSTR + qc];
            #pragma unroll
            for (int c = 0; c < 64; c += 4) {
                float4 qv = *(const float4*)(qrow + c);
                float4 rv2 = *(float4*)(rrow + c);
                rv2.x = rv2.x - qv.x; rv2.y = rv2.y - qv.y;
                rv2.z = rv2.z - qv.z; rv2.w = rv2.w - qv.w;
                *(float4*)(rrow + c) = rv2;
            }
        }
        __syncthreads();
    }
}

// ---------- replay: q_sum with the reference's exact fp32 op order ----------
__global__ void replay_kernel(const float* __restrict__ books,
                              const int* __restrict__ idxg,
                              float* __restrict__ zt) {
    size_t gid = (size_t)blockIdx.x * 256 + threadIdx.x;
    size_t tok = gid >> 6;
    int d4 = (int)(gid & 63) * 4;
    const int* ip = idxg + tok * NB;
    float4 r = *(const float4*)&zt[tok * DDIM + d4];
    float4 qs = make_float4(0.f, 0.f, 0.f, 0.f);
    #pragma unroll
    for (int b = 0; b < NB; ++b) {
        int idx = ip[b];
        float4 q = *(const float4*)&books[((size_t)b * NE + idx) * DDIM + d4];
        float t1;
        t1 = q.x - r.x; qs.x = qs.x + t1; qs.x = qs.x + r.x; r.x = r.x - q.x;
        t1 = q.y - r.y; qs.y = qs.y + t1; qs.y = qs.y + r.y; r.y = r.y - q.y;
        t1 = q.z - r.z; qs.z = qs.z + t1; qs.z = qs.z + r.z; r.z = r.z - q.z;
        t1 = q.w - r.w; qs.w = qs.w + t1; qs.w = qs.w + r.w; r.w = r.w - q.w;
    }
    *(float4*)&zt[tok * DDIM + d4] = qs;
}

// ---------- out (B,D,T) = transpose of q_sum[token][dim] ----------
__global__ void fin_kernel(const float* __restrict__ qst, float* __restrict__ out) {
    __shared__ float ld[64 * 68];
    int t0 = blockIdx.x * 64, d0 = blockIdx.y * 64, b = blockIdx.z;
    int tid = threadIdx.x;
    {
        int t = tid >> 2, d4 = (tid & 3) * 16;
        const float* rp = qst + ((size_t)b * TTOK + t0 + t) * DDIM + d0 + d4;
        #pragma unroll
        for (int c = 0; c < 16; c += 4)
            *(float4*)&ld[t * 68 + d4 + c] = *(const float4*)(rp + c);
    }
    __syncthreads();
    {
        int dd = tid >> 2, t4 = (tid & 3) * 16;
        float* op = out + ((size_t)b * DDIM + d0 + dd) * TTOK + t0 + t4;
        #pragma unroll
        for (int c = 0; c < 16; c += 4) {
            float4 o;
            o.x = ld[(size_t)(t4 + c + 0) * 68 + dd];
            o.y = ld[(size_t)(t4 + c + 1) * 68 + dd];
            o.z = ld[(size_t)(t4 + c + 2) * 68 + dd];
            o.w = ld[(size_t)(t4 + c + 3) * 68 + dd];
            *(float4*)(op + c) = o;
        }
    }
}

extern "C" void kernel_launch(void* const* d_in, const int* in_sizes, int n_in,
                              void* d_out, int out_size, void* d_ws, size_t ws_size,
                              hipStream_t stream) {
    const float* z     = (const float*)d_in[0];
    const float* books = (const float*)d_in[1];
    float* out = (float*)d_out;

    float* hg   = (float*)d_ws;                          // 8192 floats
    int*   idxg = (int*)(hg + (size_t)NB * NE);          // 65536*8 ints (2 MB)
    float* bt   = (float*)(idxg + (size_t)NTOK * NB);    // 8 MB transposed books
    float* zt   = bt + (size_t)NB * DDIM * NE;           // 64 MB token-major

    hsum_kernel<<<(NB * NE + 255) / 256, 256, 0, stream>>>(books, hg);
    tbooks_kernel<<<dim3(NE / 64, DDIM / 64, NB), 256, 0, stream>>>(books, bt);
    txin_kernel<<<dim3(TTOK / 64, DDIM / 64, BBATCH), 256, 0, stream>>>(z, zt);
    vq_main<<<NTOK / TM, 256, 0, stream>>>(books, bt, hg, zt, idxg);
    replay_kernel<<<NTOK * 64 / 256, 256, 0, stream>>>(books, idxg, zt);
    fin_kernel<<<dim3(TTOK / 64, DDIM / 64, BBATCH), 256, 0, stream>>>(zt, out);
}